// Round 1
// baseline (151.167 us; speedup 1.0000x reference)
//
#include <hip/hip_runtime.h>
#include <stdint.h>

#define DDIM 1024
#define HH 16
#define HDIM 64
#define SS 2048
#define BB 2
#define MTOT 4096

typedef short bf16x8 __attribute__((ext_vector_type(8)));
typedef float f32x4 __attribute__((ext_vector_type(4)));
typedef unsigned short u16;

__device__ __forceinline__ u16 f2bf(float f) {
  unsigned u = __builtin_bit_cast(unsigned, f);
  u = u + 0x7FFFu + ((u >> 16) & 1u);   // RNE (inputs finite)
  return (u16)(u >> 16);
}

__device__ __forceinline__ void gload16(const void* g, void* l) {
  __builtin_amdgcn_global_load_lds(
      (const __attribute__((address_space(1))) unsigned int*)g,
      (__attribute__((address_space(3))) unsigned int*)l, 16, 0, 0);
}

// ---------------- convert x: fp32 -> bf16 ----------------
__global__ void k_convert_x(const float* __restrict__ x, u16* __restrict__ xb) {
  int i = (blockIdx.x * 256 + threadIdx.x) * 4;
  float4 v = *(const float4*)(x + i);
  ushort4 o;
  o.x = f2bf(v.x); o.y = f2bf(v.y); o.z = f2bf(v.z); o.w = f2bf(v.w);
  *(ushort4*)(xb + i) = o;
}

// ---------------- transpose+convert weights: W[k][n] -> WT[n][k] bf16 ----------------
__global__ void k_transpose_w(const float* __restrict__ w0, const float* __restrict__ w1,
                              const float* __restrict__ w2, const float* __restrict__ w3,
                              u16* __restrict__ wt) {
  __shared__ float t[64][65];
  int z = blockIdx.z;
  const float* src = (z == 0) ? w0 : (z == 1) ? w1 : (z == 2) ? w2 : w3;
  u16* dst = wt + (size_t)z * DDIM * DDIM;
  int k0 = blockIdx.x * 64, n0 = blockIdx.y * 64;
  int tid = threadIdx.x;
  int c4 = tid & 15, rr = tid >> 4;
  for (int rep = 0; rep < 4; rep++) {
    int r = rr + rep * 16;
    float4 v = *(const float4*)(src + (size_t)(k0 + r) * DDIM + n0 + c4 * 4);
    t[r][c4 * 4 + 0] = v.x; t[r][c4 * 4 + 1] = v.y;
    t[r][c4 * 4 + 2] = v.z; t[r][c4 * 4 + 3] = v.w;
  }
  __syncthreads();
  for (int rep = 0; rep < 4; rep++) {
    int n = rr + rep * 16;
    ushort4 o;
    o.x = f2bf(t[c4 * 4 + 0][n]); o.y = f2bf(t[c4 * 4 + 1][n]);
    o.z = f2bf(t[c4 * 4 + 2][n]); o.w = f2bf(t[c4 * 4 + 3][n]);
    *(ushort4*)(dst + (size_t)(n0 + n) * DDIM + k0 + c4 * 4) = o;
  }
}

// ---------------- GEMM: C[m][n] = A[m][:] . BT[n][:]  (K=1024, tile 128x128, BK=64) ----------------
// MODE 0: bf16 out [M][N] (+optional bias)   MODE 1: bf16 out V-transposed [bh][hd][s]
// MODE 2: f32 out [M][N] (+bias)
template <int MODE>
__global__ __launch_bounds__(256, 2) void k_gemm(const u16* __restrict__ A,
                                                 const u16* __restrict__ BT,
                                                 const float* __restrict__ bias,
                                                 void* __restrict__ Cout) {
  __shared__ __align__(16) u16 lA[128 * 64];
  __shared__ __align__(16) u16 lB[128 * 64];
  const int tid = threadIdx.x;
  const int l = tid & 63, w = tid >> 6;
  const int wm = w >> 1, wn = w & 1;
  const int m0 = blockIdx.x * 128, n0 = blockIdx.y * 128;
  const int lr = l >> 4, lc = l & 15;

  const int srow = l >> 3;                    // row within 8-row chunk
  const int scol = ((l & 7) ^ srow) * 8;      // inverse-swizzled source col (elems)

  f32x4 acc[4][4];
  for (int mi = 0; mi < 4; mi++)
    for (int ni = 0; ni < 4; ni++)
      acc[mi][ni] = f32x4{0.f, 0.f, 0.f, 0.f};

  for (int kk = 0; kk < 16; kk++) {
    const int k0 = kk * 64;
    for (int i = 0; i < 4; i++) {
      int c = w * 4 + i;  // chunk: 8 rows x 64 cols = 1KB
      gload16(A + (size_t)(m0 + c * 8 + srow) * DDIM + k0 + scol, (char*)lA + c * 1024);
      gload16(BT + (size_t)(n0 + c * 8 + srow) * DDIM + k0 + scol, (char*)lB + c * 1024);
    }
    __syncthreads();
    for (int ks = 0; ks < 2; ks++) {
      bf16x8 af[4], bfr[4];
      for (int mi = 0; mi < 4; mi++) {
        int row = wm * 64 + mi * 16 + lc;
        int slot = (ks * 4 + lr) ^ (row & 7);
        af[mi] = *(const bf16x8*)((const char*)lA + row * 128 + slot * 16);
      }
      for (int ni = 0; ni < 4; ni++) {
        int row = wn * 64 + ni * 16 + lc;
        int slot = (ks * 4 + lr) ^ (row & 7);
        bfr[ni] = *(const bf16x8*)((const char*)lB + row * 128 + slot * 16);
      }
      for (int mi = 0; mi < 4; mi++)
        for (int ni = 0; ni < 4; ni++)
          acc[mi][ni] = __builtin_amdgcn_mfma_f32_16x16x32_bf16(af[mi], bfr[ni], acc[mi][ni], 0, 0, 0);
    }
    __syncthreads();
  }

  if (MODE == 0) {
    u16* C = (u16*)Cout;
    for (int mi = 0; mi < 4; mi++)
      for (int ni = 0; ni < 4; ni++) {
        int n = n0 + wn * 64 + ni * 16 + lc;
        float badd = bias ? bias[n] : 0.f;
        for (int r = 0; r < 4; r++) {
          int m = m0 + wm * 64 + mi * 16 + lr * 4 + r;
          C[(size_t)m * DDIM + n] = f2bf(acc[mi][ni][r] + badd);
        }
      }
  } else if (MODE == 1) {
    u16* C = (u16*)Cout;  // [bh][hd][s]
    for (int mi = 0; mi < 4; mi++)
      for (int ni = 0; ni < 4; ni++) {
        int n = n0 + wn * 64 + ni * 16 + lc;
        int h = n >> 6, hd = n & 63;
        for (int r = 0; r < 4; r++) {
          int m = m0 + wm * 64 + mi * 16 + lr * 4 + r;
          int b = m >> 11, s = m & 2047;
          C[((size_t)((b * HH + h) * HDIM + hd)) * SS + s] = f2bf(acc[mi][ni][r]);
        }
      }
  } else {
    float* C = (float*)Cout;
    for (int mi = 0; mi < 4; mi++)
      for (int ni = 0; ni < 4; ni++) {
        int n = n0 + wn * 64 + ni * 16 + lc;
        float badd = bias[n];
        for (int r = 0; r < 4; r++) {
          int m = m0 + wm * 64 + mi * 16 + lr * 4 + r;
          C[(size_t)m * DDIM + n] = acc[mi][ni][r] + badd;
        }
      }
  }
}

// ---------------- flash attention, swapped-QK^T, ALiBi + causal ----------------
// Q,K: [4096][1024] bf16 ([b,s][h,hd]);  Vt: [32][64][2048] bf16;  AO: [4096][1024] bf16
__global__ __launch_bounds__(256, 3) void k_attn(const u16* __restrict__ Q,
                                                 const u16* __restrict__ Kg,
                                                 const u16* __restrict__ Vt,
                                                 u16* __restrict__ AO) {
  __shared__ __align__(16) u16 lK[128 * 64];     // [key][hd], 8 slots/row, XOR swizzled
  __shared__ __align__(16) u16 lV[64 * 128];     // [hd][key], 16 slots/row, XOR swizzled
  __shared__ __align__(16) u16 lP[4][16 * 128];  // per-wave P [q][key], swizzled

  const int tid = threadIdx.x;
  const int l = tid & 63, w = tid >> 6;
  const int lr = l >> 4, lc = l & 15;
  const int bh = blockIdx.x;
  const int b = bh >> 4, h = bh & 15;
  // work-balanced qt remap: family yq&7 gets qt {k, 15-k, 16+k, 31-k}
  const int yq = blockIdx.y;
  const int fk = yq & 7, fj = yq >> 3;
  const int qt = (fj == 0) ? fk : (fj == 1) ? (15 - fk) : (fj == 2) ? (16 + fk) : (31 - fk);

  const float slope = exp2f(-0.5f * (float)(h + 1));
  const int q_glob = qt * 64 + w * 16 + lc;

  bf16x8 qf[2];
  for (int ks = 0; ks < 2; ks++)
    qf[ks] = *(const bf16x8*)(Q + (size_t)(b * SS + q_glob) * DDIM + h * HDIM + ks * 32 + lr * 8);

  f32x4 of[4];
  for (int mf = 0; mf < 4; mf++) of[mf] = f32x4{0.f, 0.f, 0.f, 0.f};
  float mrun = -INFINITY, lrun = 0.f;

  const int srowK = l >> 3;
  const int scolK = ((l & 7) ^ srowK) * 8;
  const int nkt = qt / 2 + 1;

  for (int kt = 0; kt < nkt; kt++) {
    for (int i = 0; i < 4; i++) {
      int c = w * 4 + i;
      // K tile: rows=key (8/chunk), 64 hd cols
      int key = kt * 128 + c * 8 + srowK;
      gload16(Kg + (size_t)(b * SS + key) * DDIM + h * HDIM + scolK, (char*)lK + c * 1024);
      // V^T tile: rows=hd (4/chunk), 128 key cols
      int hd = c * 4 + lr;
      int slot = (l & 15) ^ (hd & 7);
      gload16(Vt + ((size_t)bh * HDIM + hd) * SS + kt * 128 + slot * 8, (char*)lV + c * 1024);
    }
    __syncthreads();

    // S^T[key][q] = K . Q^T
    f32x4 sf[8];
    for (int kf = 0; kf < 8; kf++) sf[kf] = f32x4{0.f, 0.f, 0.f, 0.f};
    for (int ks = 0; ks < 2; ks++)
      for (int kf = 0; kf < 8; kf++) {
        int key = kf * 16 + lc;
        int slot = (ks * 4 + lr) ^ (key & 7);
        bf16x8 a = *(const bf16x8*)((const char*)lK + key * 128 + slot * 16);
        sf[kf] = __builtin_amdgcn_mfma_f32_16x16x32_bf16(a, qf[ks], sf[kf], 0, 0, 0);
      }

    // scale + ALiBi + causal, column(q)-wise online softmax
    float tmax = -INFINITY;
    for (int kf = 0; kf < 8; kf++)
      for (int r = 0; r < 4; r++) {
        int key = kt * 128 + kf * 16 + lr * 4 + r;
        float sv = sf[kf][r] * 0.125f - slope * (float)key;
        sv = (key > q_glob) ? -1e9f : sv;
        sf[kf][r] = sv;
        tmax = fmaxf(tmax, sv);
      }
    tmax = fmaxf(tmax, __shfl_xor(tmax, 16));
    tmax = fmaxf(tmax, __shfl_xor(tmax, 32));
    float mnew = fmaxf(mrun, tmax);
    float scale = __expf(mrun - mnew);
    lrun *= scale;
    for (int mf = 0; mf < 4; mf++)
      for (int r = 0; r < 4; r++) of[mf][r] *= scale;

    float psum = 0.f;
    for (int kf = 0; kf < 8; kf++)
      for (int r = 0; r < 4; r++) {
        float p = __expf(sf[kf][r] - mnew);
        psum += p;
        int key = kf * 16 + lr * 4 + r;  // within tile
        int slot = (key >> 3) ^ (lc & 7);
        *(u16*)((char*)lP[w] + lc * 256 + slot * 16 + (key & 7) * 2) = f2bf(p);
      }
    psum += __shfl_xor(psum, 16);
    psum += __shfl_xor(psum, 32);
    lrun += psum;
    mrun = mnew;

    // O^T[hd][q] += V^T . P^T
    for (int ks = 0; ks < 4; ks++) {
      int slotp = (ks * 4 + lr) ^ (lc & 7);
      bf16x8 pb = *(const bf16x8*)((const char*)lP[w] + lc * 256 + slotp * 16);
      for (int mf = 0; mf < 4; mf++) {
        int hd = mf * 16 + lc;
        int slotv = (ks * 4 + lr) ^ (hd & 7);
        bf16x8 va = *(const bf16x8*)((const char*)lV + hd * 256 + slotv * 16);
        of[mf] = __builtin_amdgcn_mfma_f32_16x16x32_bf16(va, pb, of[mf], 0, 0, 0);
      }
    }
    __syncthreads();
  }

  float inv = 1.f / lrun;
  for (int mf = 0; mf < 4; mf++)
    for (int r = 0; r < 4; r++) {
      int hd = mf * 16 + lr * 4 + r;
      AO[(size_t)(b * SS + q_glob) * DDIM + h * HDIM + hd] = f2bf(of[mf][r] * inv);
    }
}

extern "C" void kernel_launch(void* const* d_in, const int* in_sizes, int n_in,
                              void* d_out, int out_size, void* d_ws, size_t ws_size,
                              hipStream_t stream) {
  const float* x  = (const float*)d_in[0];
  const float* Wq = (const float*)d_in[1];
  const float* bq = (const float*)d_in[2];
  const float* Wk = (const float*)d_in[3];
  const float* Wv = (const float*)d_in[4];
  const float* Wo = (const float*)d_in[5];
  const float* bo = (const float*)d_in[6];
  float* out = (float*)d_out;

  u16* ws = (u16*)d_ws;
  const size_t MEG = 1024 * 1024;
  u16* xb = ws;                  // 4M elems (8 MB)
  u16* WT = ws + 4 * MEG;        // 4 x 1M elems (8 MB): WqT,WkT,WvT,WoT
  u16* Qb = ws + 8 * MEG;        // 4M elems
  u16* Kb = ws + 12 * MEG;       // 4M elems
  u16* Vt = ws + 16 * MEG;       // 4M elems [32][64][2048]
  u16* AO = ws + 20 * MEG;       // 4M elems

  k_convert_x<<<dim3(4096), dim3(256), 0, stream>>>(x, xb);
  k_transpose_w<<<dim3(16, 16, 4), dim3(256), 0, stream>>>(Wq, Wk, Wv, Wo, WT);
  k_gemm<0><<<dim3(32, 8), dim3(256), 0, stream>>>(xb, WT + 0 * MEG, bq, (void*)Qb);
  k_gemm<0><<<dim3(32, 8), dim3(256), 0, stream>>>(xb, WT + 1 * MEG, (const float*)nullptr, (void*)Kb);
  k_gemm<1><<<dim3(32, 8), dim3(256), 0, stream>>>(xb, WT + 2 * MEG, (const float*)nullptr, (void*)Vt);
  k_attn<<<dim3(32, 32), dim3(256), 0, stream>>>(Qb, Kb, Vt, AO);
  k_gemm<2><<<dim3(32, 8), dim3(256), 0, stream>>>(AO, WT + 3 * MEG, bo, (void*)out);
}

// Round 3
// 123.669 us; speedup vs baseline: 1.2224x; 1.2224x over previous
//
#include <hip/hip_runtime.h>
#include <stdint.h>

#define DDIM 1024
#define HH 16
#define HDIM 64
#define SS 2048

typedef short bf16x8 __attribute__((ext_vector_type(8)));
typedef short bf16x4 __attribute__((ext_vector_type(4)));
typedef float f32x4 __attribute__((ext_vector_type(4)));
typedef unsigned short u16;

__device__ __forceinline__ unsigned f2bf(float f) {
  unsigned u = __builtin_bit_cast(unsigned, f);
  u = u + 0x7FFFu + ((u >> 16) & 1u);   // RNE (inputs finite)
  return u >> 16;
}

__device__ __forceinline__ void mfma16(f32x4& c, bf16x4 a, bf16x4 b) {
  asm("v_mfma_f32_16x16x16_bf16 %0, %1, %2, %0" : "+v"(c) : "v"(a), "v"(b));
}

__device__ __forceinline__ void gload16(const void* g, void* l) {
  __builtin_amdgcn_global_load_lds(
      (const __attribute__((address_space(1))) unsigned int*)g,
      (__attribute__((address_space(3))) unsigned int*)l, 16, 0, 0);
}

// ---------------- convert x: fp32 -> bf16 ----------------
__global__ void k_convert_x(const float* __restrict__ x, u16* __restrict__ xb) {
  int i = (blockIdx.x * 256 + threadIdx.x) * 4;
  float4 v = *(const float4*)(x + i);
  ushort4 o;
  o.x = (u16)f2bf(v.x); o.y = (u16)f2bf(v.y); o.z = (u16)f2bf(v.z); o.w = (u16)f2bf(v.w);
  *(ushort4*)(xb + i) = o;
}

// ---------------- transpose+convert weights: W[k][n] -> WT[n][k] bf16 ----------------
__global__ void k_transpose_w(const float* __restrict__ w0, const float* __restrict__ w1,
                              const float* __restrict__ w2, const float* __restrict__ w3,
                              u16* __restrict__ wt) {
  __shared__ float t[64][65];
  int z = blockIdx.z;
  const float* src = (z == 0) ? w0 : (z == 1) ? w1 : (z == 2) ? w2 : w3;
  u16* dst = wt + (size_t)z * DDIM * DDIM;
  int k0 = blockIdx.x * 64, n0 = blockIdx.y * 64;
  int tid = threadIdx.x;
  int c4 = tid & 15, rr = tid >> 4;
  for (int rep = 0; rep < 4; rep++) {
    int r = rr + rep * 16;
    float4 v = *(const float4*)(src + (size_t)(k0 + r) * DDIM + n0 + c4 * 4);
    t[r][c4 * 4 + 0] = v.x; t[r][c4 * 4 + 1] = v.y;
    t[r][c4 * 4 + 2] = v.z; t[r][c4 * 4 + 3] = v.w;
  }
  __syncthreads();
  for (int rep = 0; rep < 4; rep++) {
    int n = rr + rep * 16;
    ushort4 o;
    o.x = (u16)f2bf(t[c4 * 4 + 0][n]); o.y = (u16)f2bf(t[c4 * 4 + 1][n]);
    o.z = (u16)f2bf(t[c4 * 4 + 2][n]); o.w = (u16)f2bf(t[c4 * 4 + 3][n]);
    *(ushort4*)(dst + (size_t)(n0 + n) * DDIM + k0 + c4 * 4) = o;
  }
}

// ---------------- GEMM: tile 128x128, BK=64, K=1024; A[m][k], BT[n][k] bf16 ----------------
// MODE 0: fused QKV (grid y 0..23; which=blockIdx.y>>3: 0->Qb (+bias), 1->Kb, 2->Vt transposed)
// MODE 1: fp32 out + bias (final projection)
template <int MODE>
__global__ __launch_bounds__(256, 2) void k_gemm(const u16* __restrict__ A,
                                                 const u16* __restrict__ BT,
                                                 const float* __restrict__ bias,
                                                 void* __restrict__ O0,
                                                 void* __restrict__ O1,
                                                 void* __restrict__ O2) {
  __shared__ __align__(16) u16 lA[128 * 64];
  __shared__ __align__(16) u16 lB[128 * 64];
  const int tid = threadIdx.x;
  const int l = tid & 63, w = tid >> 6;
  const int wm = w >> 1, wn = w & 1;
  const int m0 = blockIdx.x * 128, n0 = blockIdx.y * 128;
  const int lr = l >> 4, lc = l & 15;

  const int srow = l >> 3;
  const int scol = ((l & 7) ^ srow) * 8;

  f32x4 acc[4][4];
  for (int mi = 0; mi < 4; mi++)
    for (int ni = 0; ni < 4; ni++)
      acc[mi][ni] = f32x4{0.f, 0.f, 0.f, 0.f};

  for (int kk = 0; kk < 16; kk++) {
    const int k0 = kk * 64;
    for (int i = 0; i < 4; i++) {
      int c = w * 4 + i;
      gload16(A + (size_t)(m0 + c * 8 + srow) * DDIM + k0 + scol, (char*)lA + c * 1024);
      gload16(BT + (size_t)(n0 + c * 8 + srow) * DDIM + k0 + scol, (char*)lB + c * 1024);
    }
    __syncthreads();
    for (int ks = 0; ks < 2; ks++) {
      bf16x8 af[4], bfr[4];
      for (int mi = 0; mi < 4; mi++) {
        int row = wm * 64 + mi * 16 + lc;
        int slot = (ks * 4 + lr) ^ (row & 7);
        af[mi] = *(const bf16x8*)((const char*)lA + row * 128 + slot * 16);
      }
      for (int ni = 0; ni < 4; ni++) {
        int row = wn * 64 + ni * 16 + lc;
        int slot = (ks * 4 + lr) ^ (row & 7);
        bfr[ni] = *(const bf16x8*)((const char*)lB + row * 128 + slot * 16);
      }
      for (int mi = 0; mi < 4; mi++)
        for (int ni = 0; ni < 4; ni++)
          acc[mi][ni] = __builtin_amdgcn_mfma_f32_16x16x32_bf16(af[mi], bfr[ni], acc[mi][ni], 0, 0, 0);
    }
    __syncthreads();
  }

  if (MODE == 0) {
    const int which = blockIdx.y >> 3;   // uniform per block
    if (which == 0) {
      u16* C = (u16*)O0;
      for (int mi = 0; mi < 4; mi++)
        for (int ni = 0; ni < 4; ni++) {
          int nl = (n0 + wn * 64 + ni * 16 + lc) & 1023;
          float badd = bias[nl];
          for (int r = 0; r < 4; r++) {
            int m = m0 + wm * 64 + mi * 16 + lr * 4 + r;
            C[(size_t)m * DDIM + nl] = (u16)f2bf(acc[mi][ni][r] + badd);
          }
        }
    } else if (which == 1) {
      u16* C = (u16*)O1;
      for (int mi = 0; mi < 4; mi++)
        for (int ni = 0; ni < 4; ni++) {
          int nl = (n0 + wn * 64 + ni * 16 + lc) & 1023;
          for (int r = 0; r < 4; r++) {
            int m = m0 + wm * 64 + mi * 16 + lr * 4 + r;
            C[(size_t)m * DDIM + nl] = (u16)f2bf(acc[mi][ni][r]);
          }
        }
    } else {
      u16* C = (u16*)O2;  // [bh][hd][s]
      for (int mi = 0; mi < 4; mi++)
        for (int ni = 0; ni < 4; ni++) {
          int nl = (n0 + wn * 64 + ni * 16 + lc) & 1023;
          int h = nl >> 6, hd = nl & 63;
          int m = m0 + wm * 64 + mi * 16 + lr * 4;
          int b = m >> 11, s = m & 2047;
          unsigned d0 = f2bf(acc[mi][ni][0]) | (f2bf(acc[mi][ni][1]) << 16);
          unsigned d1 = f2bf(acc[mi][ni][2]) | (f2bf(acc[mi][ni][3]) << 16);
          u16* p = C + ((size_t)((b * HH + h) * HDIM + hd)) * SS + s;
          *(unsigned*)(p) = d0;
          *(unsigned*)(p + 2) = d1;
        }
    }
  } else {
    float* C = (float*)O0;
    for (int mi = 0; mi < 4; mi++)
      for (int ni = 0; ni < 4; ni++) {
        int n = n0 + wn * 64 + ni * 16 + lc;
        float badd = bias[n];
        for (int r = 0; r < 4; r++) {
          int m = m0 + wm * 64 + mi * 16 + lr * 4 + r;
          C[(size_t)m * DDIM + n] = acc[mi][ni][r] + badd;
        }
      }
  }
}

// ---------------- flash attention tile body (R1 numerics, R2 structure) ----------------
// natural-domain softmax: sv = S*0.125 - slope*key; p = __expf(sv - m); P stays in regs
__device__ __forceinline__ void attn_tile(int kt, bool masked, int kfhi,
                                          const char* lKc, const char* lVc,
                                          const bf16x8 qf[2], f32x4 of[4],
                                          float& mrun, float& lrun,
                                          float slope, int lr, int lc, int q_glob) {
  // S^T[key][q] = K . Q^T
  f32x4 sf[8];
#pragma unroll
  for (int kf = 0; kf < 8; kf++) sf[kf] = f32x4{0.f, 0.f, 0.f, 0.f};
#pragma unroll
  for (int ks = 0; ks < 2; ks++)
#pragma unroll
    for (int kf = 0; kf < 8; kf++) {
      if (kf >= kfhi) continue;
      int key = kf * 16 + lc;
      int slot = (ks * 4 + lr) ^ (lc & 7);
      bf16x8 a = *(const bf16x8*)(lKc + key * 128 + slot * 16);
      sf[kf] = __builtin_amdgcn_mfma_f32_16x16x32_bf16(a, qf[ks], sf[kf], 0, 0, 0);
    }

  // scale + ALiBi + causal mask + column max (exactly R1's formulas)
  float tmax = -INFINITY;
#pragma unroll
  for (int kf = 0; kf < 8; kf++) {
    if (kf >= kfhi) continue;
#pragma unroll
    for (int r = 0; r < 4; r++) {
      int key = kt * 128 + kf * 16 + lr * 4 + r;
      float sv = sf[kf][r] * 0.125f - slope * (float)key;
      if (masked && key > q_glob) sv = -1e9f;
      sf[kf][r] = sv;
      tmax = fmaxf(tmax, sv);
    }
  }
  tmax = fmaxf(tmax, __shfl_xor(tmax, 16));
  tmax = fmaxf(tmax, __shfl_xor(tmax, 32));

  // conditional rescale (exact: skipping is the corr==1 case)
  if (tmax > mrun) {
    float corr = __expf(mrun - tmax);
    lrun *= corr;
#pragma unroll
    for (int mf = 0; mf < 4; mf++) {
      of[mf][0] *= corr; of[mf][1] *= corr; of[mf][2] *= corr; of[mf][3] *= corr;
    }
    mrun = tmax;
  }

  // p = exp(sv - m); round to bf16 (RNE) once, use SAME rounded value for
  // both the PV numerator and the denominator (consistency cancellation)
  f32x4 ps = f32x4{0.f, 0.f, 0.f, 0.f};
  bf16x4 pb[8];
#pragma unroll
  for (int kf = 0; kf < 8; kf++) {
    if (kf >= kfhi) continue;
    unsigned a0 = f2bf(__expf(sf[kf][0] - mrun));
    unsigned a1 = f2bf(__expf(sf[kf][1] - mrun));
    unsigned a2 = f2bf(__expf(sf[kf][2] - mrun));
    unsigned a3 = f2bf(__expf(sf[kf][3] - mrun));
    uint2 uu;
    uu.x = a0 | (a1 << 16);
    uu.y = a2 | (a3 << 16);
    pb[kf] = __builtin_bit_cast(bf16x4, uu);
    ps[0] += __builtin_bit_cast(float, a0 << 16);
    ps[1] += __builtin_bit_cast(float, a1 << 16);
    ps[2] += __builtin_bit_cast(float, a2 << 16);
    ps[3] += __builtin_bit_cast(float, a3 << 16);
  }
  float psum = (ps[0] + ps[1]) + (ps[2] + ps[3]);
  psum += __shfl_xor(psum, 16);
  psum += __shfl_xor(psum, 32);
  lrun += psum;

  // O^T[hd][q] += V^T . P   (A = V b64 frags, B = in-register P)
#pragma unroll
  for (int kf = 0; kf < 8; kf++) {
    if (kf >= kfhi) continue;
    int g2 = (kf << 1) + (lr >> 1);
#pragma unroll
    for (int mf = 0; mf < 4; mf++) {
      int hd = mf * 16 + lc;
      int byte = hd * 256 + ((g2 ^ (hd & 7)) << 4) + ((lr & 1) << 3);
      bf16x4 va = *(const bf16x4*)(lVc + byte);
      mfma16(of[mf], va, pb[kf]);
    }
  }
}

__global__ __launch_bounds__(256, 4) void k_attn(const u16* __restrict__ Q,
                                                 const u16* __restrict__ Kg,
                                                 const u16* __restrict__ Vt,
                                                 u16* __restrict__ AO) {
  __shared__ __align__(16) u16 lK[128 * 64];  // [key][hd], XOR-swizzled 16B slots
  __shared__ __align__(16) u16 lV[64 * 128];  // [hd][key], XOR-swizzled 16B slots

  const int tid = threadIdx.x;
  const int l = tid & 63, w = tid >> 6;
  const int lr = l >> 4, lc = l & 15;
  const int bh = blockIdx.x;
  const int b = bh >> 4, h = bh & 15;
  const int yq = blockIdx.y;
  const int fk = yq & 7, fj = yq >> 3;
  const int qt = (fj == 0) ? fk : (fj == 1) ? (15 - fk) : (fj == 2) ? (16 + fk) : (31 - fk);

  const float slope = exp2f(-0.5f * (float)(h + 1));
  const int q_glob = qt * 64 + w * 16 + lc;

  bf16x8 qf[2];
#pragma unroll
  for (int ks = 0; ks < 2; ks++)
    qf[ks] = *(const bf16x8*)(Q + (size_t)(b * SS + q_glob) * DDIM + h * HDIM + ks * 32 + lr * 8);

  f32x4 of[4];
#pragma unroll
  for (int mf = 0; mf < 4; mf++) of[mf] = f32x4{0.f, 0.f, 0.f, 0.f};
  float mrun = -INFINITY, lrun = 0.f;

  const int srowK = l >> 3;
  const int scolK = ((l & 7) ^ srowK) * 8;
  const int nkt = qt / 2 + 1;

  auto stage = [&](int kt) {
#pragma unroll
    for (int i = 0; i < 4; i++) {
      int c = w * 4 + i;
      gload16(Kg + (size_t)(b * SS + kt * 128 + c * 8 + srowK) * DDIM + h * HDIM + scolK,
              (char*)lK + c * 1024);
      int hd = c * 4 + lr;
      gload16(Vt + ((size_t)bh * HDIM + hd) * SS + kt * 128 + (((l & 15) ^ (hd & 7)) << 3),
              (char*)lV + c * 1024);
    }
  };

  for (int kt = 0; kt < nkt - 1; kt++) {
    stage(kt);
    __syncthreads();
    attn_tile(kt, false, 8, (const char*)lK, (const char*)lV, qf, of, mrun, lrun,
              slope, lr, lc, q_glob);
    __syncthreads();
  }
  stage(nkt - 1);
  __syncthreads();
  if (qt & 1)
    attn_tile(nkt - 1, true, 8, (const char*)lK, (const char*)lV, qf, of, mrun, lrun,
              slope, lr, lc, q_glob);
  else
    attn_tile(nkt - 1, true, 4, (const char*)lK, (const char*)lV, qf, of, mrun, lrun,
              slope, lr, lc, q_glob);

  float inv = 1.f / lrun;
  u16* obase = AO + (size_t)(b * SS + q_glob) * DDIM + h * HDIM;
#pragma unroll
  for (int mf = 0; mf < 4; mf++) {
    uint2 uu;
    uu.x = f2bf(of[mf][0] * inv) | (f2bf(of[mf][1] * inv) << 16);
    uu.y = f2bf(of[mf][2] * inv) | (f2bf(of[mf][3] * inv) << 16);
    *(uint2*)(obase + mf * 16 + lr * 4) = uu;
  }
}

extern "C" void kernel_launch(void* const* d_in, const int* in_sizes, int n_in,
                              void* d_out, int out_size, void* d_ws, size_t ws_size,
                              hipStream_t stream) {
  const float* x  = (const float*)d_in[0];
  const float* Wq = (const float*)d_in[1];
  const float* bq = (const float*)d_in[2];
  const float* Wk = (const float*)d_in[3];
  const float* Wv = (const float*)d_in[4];
  const float* Wo = (const float*)d_in[5];
  const float* bo = (const float*)d_in[6];
  float* out = (float*)d_out;

  u16* ws = (u16*)d_ws;
  const size_t MEG = 1024 * 1024;
  u16* xb = ws;                  // 4M elems
  u16* WT = ws + 4 * MEG;        // 4 x 1M elems: WqT,WkT,WvT,WoT
  u16* Qb = ws + 8 * MEG;        // 4M
  u16* Kb = ws + 12 * MEG;       // 4M
  u16* Vt = ws + 16 * MEG;       // 4M  [32][64][2048]
  u16* AO = ws + 20 * MEG;       // 4M

  k_convert_x<<<dim3(4096), dim3(256), 0, stream>>>(x, xb);
  k_transpose_w<<<dim3(16, 16, 4), dim3(256), 0, stream>>>(Wq, Wk, Wv, Wo, WT);
  k_gemm<0><<<dim3(32, 24), dim3(256), 0, stream>>>(xb, WT, bq, (void*)Qb, (void*)Kb, (void*)Vt);
  k_attn<<<dim3(32, 32), dim3(256), 0, stream>>>(Qb, Kb, Vt, AO);
  k_gemm<1><<<dim3(32, 8), dim3(256), 0, stream>>>(AO, WT + 3 * MEG, bo, (void*)out, nullptr, nullptr);
}